// Round 6
// baseline (1318.427 us; speedup 1.0000x reference)
//
#include <hip/hip_runtime.h>
#include <hip/hip_fp16.h>

#define DD 64
#define HC 384     // 2*D*L
#define SS 32
#define BINW 128   // nodes per bin (bin = dst >> 7); requires N < 65536
#define BSH 7
#define NB 512     // max bins (N <= 65536)
#define CHUNK 4096 // edges per partition block

// ---------------- bin histogram ----------------
__global__ __launch_bounds__(256) void bin_count_kernel(
    const int* __restrict__ ei, int* __restrict__ bin_cnt, int E)
{
  __shared__ int cnt[NB];
  int t = threadIdx.x;
  cnt[t] = 0; cnt[t + 256] = 0;
  __syncthreads();
  for (int e = blockIdx.x * 256 + t; e < E; e += gridDim.x * 256)
    atomicAdd(&cnt[ei[E + e] >> BSH], 1);
  __syncthreads();
  if (cnt[t] > 0)       atomicAdd(&bin_cnt[t], cnt[t]);
  if (cnt[t + 256] > 0) atomicAdd(&bin_cnt[t + 256], cnt[t + 256]);
}

// exclusive scan of <=512 bin counts (strip-2 per thread), one block
__global__ __launch_bounds__(256) void bin_scan_kernel(
    const int* __restrict__ bin_cnt, int* __restrict__ bin_base,
    int* __restrict__ bin_cur, int nbins, int E)
{
  __shared__ int s[256];
  int t = threadIdx.x;
  int i0 = 2 * t, i1 = 2 * t + 1;
  int c0 = (i0 < nbins) ? bin_cnt[i0] : 0;
  int c1 = (i1 < nbins) ? bin_cnt[i1] : 0;
  int sum = c0 + c1;
  s[t] = sum;
  __syncthreads();
  for (int o = 1; o < 256; o <<= 1) {
    int u = (t >= o) ? s[t - o] : 0;
    __syncthreads();
    s[t] += u;
    __syncthreads();
  }
  int excl = s[t] - sum;
  if (i0 < nbins) { bin_base[i0] = excl;      bin_cur[i0] = excl; }
  if (i1 < nbins) { bin_base[i1] = excl + c0; bin_cur[i1] = excl + c0; }
  if (t == 0) bin_base[nbins] = E;
}

// partition edges into dst bins; packed = (src | dst<<16, weight_bits)
__global__ __launch_bounds__(256) void bin_part_kernel(
    const int* __restrict__ ei, const float* __restrict__ ew,
    int* __restrict__ bin_cur, uint2* __restrict__ ebin, int E)
{
  __shared__ uint2 spk[CHUNK];                       // 32 KB
  __shared__ int bcnt[NB], boff[NB], bcur[NB], gbase[NB], stmp[256];
  int t = threadIdx.x;
  int e0 = blockIdx.x * CHUNK;
  int m = min(CHUNK, E - e0);
  bcnt[t] = 0; bcnt[t + 256] = 0;
  __syncthreads();
  for (int i = t; i < m; i += 256)
    atomicAdd(&bcnt[ei[E + e0 + i] >> BSH], 1);
  __syncthreads();
  int c0 = bcnt[2 * t], c1 = bcnt[2 * t + 1];
  int sum = c0 + c1;
  stmp[t] = sum;
  __syncthreads();
  for (int o = 1; o < 256; o <<= 1) {
    int u = (t >= o) ? stmp[t - o] : 0;
    __syncthreads();
    stmp[t] += u;
    __syncthreads();
  }
  int excl = stmp[t] - sum;
  boff[2 * t] = excl;          bcur[2 * t] = excl;
  boff[2 * t + 1] = excl + c0; bcur[2 * t + 1] = excl + c0;
  if (c0 > 0) gbase[2 * t] = atomicAdd(&bin_cur[2 * t], c0);
  if (c1 > 0) gbase[2 * t + 1] = atomicAdd(&bin_cur[2 * t + 1], c1);
  __syncthreads();
  for (int i = t; i < m; i += 256) {
    unsigned d = (unsigned)ei[E + e0 + i];
    int b = d >> BSH;
    int p = atomicAdd(&bcur[b], 1);
    spk[p] = make_uint2((unsigned)ei[e0 + i] | (d << 16),
                        __float_as_uint(ew[e0 + i]));
  }
  __syncthreads();
  // staged items are grouped by bin -> per-bin contiguous global writes
  for (int i = t; i < m; i += 256) {
    uint2 w = spk[i];
    int b = w.x >> 23;             // dst>>7 (unsigned shift)
    ebin[gbase[b] + (i - boff[b])] = w;
  }
}

// ---------------- fp32 -> fp16 row cache ----------------
__global__ __launch_bounds__(256) void tohalf_kernel(
    const float* __restrict__ x, __half* __restrict__ hh, int total)
{
  int i = (blockIdx.x * 256 + threadIdx.x) * 8;
  if (i >= total) return;
  float4 a = *(const float4*)(x + i);
  float4 b = *(const float4*)(x + i + 4);
  __half2 o[4];
  o[0] = __floats2half2_rn(a.x, a.y);
  o[1] = __floats2half2_rn(a.z, a.w);
  o[2] = __floats2half2_rn(b.x, b.y);
  o[3] = __floats2half2_rn(b.z, b.w);
  *(float4*)(hh + i) = *(float4*)o;
}

// ---------------- binned aggregation + self-term ----------------
// One block per 128-node bin. 32 KB LDS fp32 accumulator, word-rotated
// (+dl mod 64) so ds_add_f32 banks spread across subgroup dst offsets.
// Wave = 8 edge-subgroups x 8 lanes; lane holds 8 channels (16 B fp16 row).
__global__ __launch_bounds__(256) void agg_kernel(
    const __half* __restrict__ hh, const float* __restrict__ h,
    const uint2* __restrict__ ebin, const int* __restrict__ bin_base,
    const float* __restrict__ epsv, float* __restrict__ z, int layer, int N)
{
  __shared__ float acc[BINW * DD];   // 32 KB
  const int t = threadIdx.x;
  const int wave = t >> 6;
  const int lane = t & 63;
  const int sub = lane >> 3;
  const int ch0 = (lane & 7) * 8;
  const int b = blockIdx.x;
  for (int i = t; i < BINW * DD; i += 256) acc[i] = 0.0f;
  __syncthreads();

  const int ebeg = bin_base[b], eend = bin_base[b + 1];
  int i = ebeg + wave * 8 + sub;
  for (; i + 32 < eend; i += 64) {
    uint2 l0 = ebin[i];
    uint2 l1 = ebin[i + 32];
    int s0 = l0.x & 0xffff, d0 = (l0.x >> 16) & (BINW - 1);
    int s1 = l1.x & 0xffff, d1 = (l1.x >> 16) & (BINW - 1);
    float w0 = __uint_as_float(l0.y), w1 = __uint_as_float(l1.y);
    float4 r0 = *(const float4*)(hh + (size_t)s0 * DD + ch0);
    float4 r1 = *(const float4*)(hh + (size_t)s1 * DD + ch0);
    const __half2* H0 = (const __half2*)&r0;
    const __half2* H1 = (const __half2*)&r1;
    #pragma unroll
    for (int j = 0; j < 4; ++j) {
      float2 f0 = __half22float2(H0[j]);
      float2 f1 = __half22float2(H1[j]);
      atomicAdd(&acc[d0 * DD + ((ch0 + 2 * j     + d0) & 63)], w0 * f0.x);
      atomicAdd(&acc[d0 * DD + ((ch0 + 2 * j + 1 + d0) & 63)], w0 * f0.y);
      atomicAdd(&acc[d1 * DD + ((ch0 + 2 * j     + d1) & 63)], w1 * f1.x);
      atomicAdd(&acc[d1 * DD + ((ch0 + 2 * j + 1 + d1) & 63)], w1 * f1.y);
    }
  }
  for (; i < eend; i += 32) {
    uint2 l0 = ebin[i];
    int s0 = l0.x & 0xffff, d0 = (l0.x >> 16) & (BINW - 1);
    float w0 = __uint_as_float(l0.y);
    float4 r0 = *(const float4*)(hh + (size_t)s0 * DD + ch0);
    const __half2* H0 = (const __half2*)&r0;
    #pragma unroll
    for (int j = 0; j < 4; ++j) {
      float2 f0 = __half22float2(H0[j]);
      atomicAdd(&acc[d0 * DD + ((ch0 + 2 * j     + d0) & 63)], w0 * f0.x);
      atomicAdd(&acc[d0 * DD + ((ch0 + 2 * j + 1 + d0) & 63)], w0 * f0.y);
    }
  }
  __syncthreads();

  const float e1 = 1.0f + epsv[layer];
  const int nb0 = b * BINW;
  for (int idx = t; idx < BINW * DD; idx += 256) {
    int r = idx >> 6, c = idx & 63;
    int n = nb0 + r;
    if (n < N)
      z[(size_t)n * DD + c] =
          fmaf(e1, h[(size_t)n * DD + c], acc[r * DD + ((c + r) & 63)]);
  }
}

// ---------------- per-node GIN MLP + pooling ----------------
__global__ __launch_bounds__(256) void node_kernel(
    float* __restrict__ z, __half* __restrict__ hhalf,
    const float* __restrict__ W1, const float* __restrict__ b1,
    const float* __restrict__ gamma, const float* __restrict__ beta,
    const float* __restrict__ bnm, const float* __restrict__ bnv,
    const float* __restrict__ W2, const float* __restrict__ b2,
    const float* __restrict__ pmask, const int* __restrict__ batch,
    float* __restrict__ hcat, int layer, int N, int write_half)
{
  __shared__ float tileZ[DD * DD];
  __shared__ float tileT[DD * DD];
  const int wave = threadIdx.x >> 6;
  const int lane = threadIdx.x & 63;
  const int n0 = blockIdx.x * 64;
  const int c0 = __builtin_amdgcn_readfirstlane(wave * 16);  // SGPR
  const float* W1l = W1 + layer * DD * DD;
  const float* W2l = W2 + layer * DD * DD;

  #pragma unroll
  for (int i = 0; i < 16; ++i) {
    int r = c0 + i;
    int n = n0 + r;
    float v = (n < N) ? z[(size_t)n * DD + lane] : 0.0f;
    tileZ[r * DD + ((lane + r) & 63)] = v;
  }
  __syncthreads();

  float t[16];
  #pragma unroll
  for (int cc = 0; cc < 16; ++cc) t[cc] = 0.0f;
  #pragma unroll 2
  for (int k = 0; k < DD; ++k) {
    float zk = tileZ[lane * DD + ((k + lane) & 63)];
    #pragma unroll
    for (int cc = 0; cc < 16; ++cc)
      t[cc] = fmaf(zk, W1l[k * DD + c0 + cc], t[cc]);   // scalar W
  }
  #pragma unroll
  for (int cc = 0; cc < 16; ++cc) {
    int c = c0 + cc;
    float A = gamma[layer * DD + c] * rsqrtf(bnv[layer * DD + c] + 1e-5f);
    float B = fmaf(b1[layer * DD + c] - bnm[layer * DD + c], A,
                   beta[layer * DD + c]);
    tileT[lane * DD + ((c + lane) & 63)] = fmaxf(fmaf(t[cc], A, B), 0.0f);
  }
  __syncthreads();

  #pragma unroll
  for (int cc = 0; cc < 16; ++cc) t[cc] = 0.0f;
  #pragma unroll 2
  for (int k = 0; k < DD; ++k) {
    float zk = tileT[lane * DD + ((k + lane) & 63)];
    #pragma unroll
    for (int cc = 0; cc < 16; ++cc)
      t[cc] = fmaf(zk, W2l[k * DD + c0 + cc], t[cc]);   // scalar W
  }
  #pragma unroll
  for (int cc = 0; cc < 16; ++cc) {
    int c = c0 + cc;
    tileZ[lane * DD + ((c + lane) & 63)] =
        fmaxf(t[cc] + b2[layer * DD + c], 0.0f);
  }
  __syncthreads();

  float accp = 0.0f;
  int gcur = -1;
  for (int i = 0; i < 16; ++i) {
    int r = c0 + i;
    int n = n0 + r;
    if (n >= N) break;
    float v = tileZ[r * DD + ((lane + r) & 63)];
    z[(size_t)n * DD + lane] = v;
    if (write_half) hhalf[(size_t)n * DD + lane] = __float2half(v);
    int g = batch[n];
    if (g != gcur) {
      if (gcur >= 0) atomicAdd(&hcat[gcur * HC + layer * 128 + lane], accp);
      gcur = g; accp = 0.0f;
    }
    accp = fmaf(v, pmask[n], accp);
  }
  if (gcur >= 0) atomicAdd(&hcat[gcur * HC + layer * 128 + lane], accp);
}

// ---------------- center-node gather ----------------
__global__ __launch_bounds__(256) void center_kernel(
    const float* __restrict__ h, const int* __restrict__ mapping,
    float* __restrict__ hcat, int layer, int G)
{
  int gid = blockIdx.x * 256 + threadIdx.x;
  int g = gid >> 4, q = (gid & 15) * 4;
  if (g >= G) return;
  float4 v = *(const float4*)(h + (size_t)mapping[g] * DD + q);
  *(float4*)(hcat + g * HC + layer * 128 + 64 + q) = v;
}

// ---------------- final linear ----------------
__global__ __launch_bounds__(256) void final_kernel(
    const float* __restrict__ hcat, const float* __restrict__ lw,
    const float* __restrict__ lb, float* __restrict__ out, int G)
{
  int gid = blockIdx.x * 256 + threadIdx.x;
  int g = gid >> 5, s = gid & 31;
  if (g >= G) return;
  float acc = lb[s];
  #pragma unroll 4
  for (int j = 0; j < HC; ++j)
    acc = fmaf(hcat[g * HC + j], lw[j * SS + s], acc);
  out[g * SS + s] = acc;
}

extern "C" void kernel_launch(void* const* d_in, const int* in_sizes, int n_in,
                              void* d_out, int out_size, void* d_ws, size_t ws_size,
                              hipStream_t stream)
{
  const float* x     = (const float*)d_in[0];
  const float* ew    = (const float*)d_in[1];
  const float* pmask = (const float*)d_in[2];
  const float* W1    = (const float*)d_in[3];
  const float* b1    = (const float*)d_in[4];
  const float* gma   = (const float*)d_in[5];
  const float* bta   = (const float*)d_in[6];
  const float* bnm   = (const float*)d_in[7];
  const float* bnv   = (const float*)d_in[8];
  const float* W2    = (const float*)d_in[9];
  const float* b2    = (const float*)d_in[10];
  const float* epsv  = (const float*)d_in[11];
  const float* lw    = (const float*)d_in[12];
  const float* lb    = (const float*)d_in[13];
  const int*   ei    = (const int*)d_in[14];
  const int*   batch = (const int*)d_in[15];
  const int*   mapping = (const int*)d_in[16];

  const int N = in_sizes[2];     // 50000 (< 65536: required for packing)
  const int E = in_sizes[1];
  const int G = in_sizes[16];
  const int nbins = (N + BINW - 1) / BINW;
  const int nchunks = (E + CHUNK - 1) / CHUNK;

  float*  bufA = (float*)d_ws;                        // N*DD
  float*  bufB = bufA + (size_t)N * DD;               // N*DD
  float*  hcat = bufB + (size_t)N * DD;               // G*HC
  int*    bin_cnt  = (int*)(hcat + (size_t)G * HC);   // NB
  int*    bin_base = bin_cnt + NB;                    // NB+1
  int*    bin_cur  = bin_base + NB + 1;               // NB (+pad to even)
  uint2*  ebin   = (uint2*)(bin_cur + NB + 1);        // E
  __half* hhalf  = (__half*)(ebin + (size_t)E);       // N*DD
  float* fout = (float*)d_out;

  // ---- binned edge build ----
  hipMemsetAsync(bin_cnt, 0, NB * sizeof(int), stream);
  bin_count_kernel<<<256, 256, 0, stream>>>(ei, bin_cnt, E);
  bin_scan_kernel<<<1, 256, 0, stream>>>(bin_cnt, bin_base, bin_cur, nbins, E);
  bin_part_kernel<<<nchunks, 256, 0, stream>>>(ei, ew, bin_cur, ebin, E);

  hipMemsetAsync(hcat, 0, (size_t)G * HC * sizeof(float), stream);
  tohalf_kernel<<<(N * DD / 8 + 255) / 256, 256, 0, stream>>>(x, hhalf, N * DD);

  // ---- 3 GIN layers ----
  const float* hsrc = x;
  float* zbuf = bufA;
  for (int layer = 0; layer < 3; ++layer) {
    agg_kernel<<<nbins, 256, 0, stream>>>(
        hhalf, hsrc, ebin, bin_base, epsv, zbuf, layer, N);
    node_kernel<<<(N + 63) / 64, 256, 0, stream>>>(
        zbuf, hhalf, W1, b1, gma, bta, bnm, bnv, W2, b2,
        pmask, batch, hcat, layer, N, (layer < 2) ? 1 : 0);
    center_kernel<<<(G * DD / 4 + 255) / 256, 256, 0, stream>>>(
        zbuf, mapping, hcat, layer, G);
    hsrc = zbuf;
    zbuf = (zbuf == bufA) ? bufB : bufA;
  }
  final_kernel<<<(G * SS + 255) / 256, 256, 0, stream>>>(hcat, lw, lb, fout, G);
}

// Round 7
// 364.685 us; speedup vs baseline: 3.6153x; 3.6153x over previous
//
#include <hip/hip_runtime.h>
#include <hip/hip_fp16.h>

#define DD 64
#define HC 384     // 2*D*L
#define SS 32
#define BINW 256   // nodes per bin (bin = dst >> 8); requires N < 65536
#define BSH 8
#define CHUNK 4096 // edges per partition block

// ---------------- bin histogram ----------------
__global__ __launch_bounds__(256) void bin_count_kernel(
    const int* __restrict__ ei, int* __restrict__ bin_cnt, int E)
{
  __shared__ int cnt[256];
  int t = threadIdx.x;
  cnt[t] = 0;
  __syncthreads();
  for (int e = blockIdx.x * 256 + t; e < E; e += gridDim.x * 256)
    atomicAdd(&cnt[ei[E + e] >> BSH], 1);
  __syncthreads();
  if (cnt[t] > 0) atomicAdd(&bin_cnt[t], cnt[t]);
}

__global__ __launch_bounds__(256) void bin_scan_kernel(
    const int* __restrict__ bin_cnt, int* __restrict__ bin_base,
    int* __restrict__ bin_cur, int nbins, int E)
{
  __shared__ int s[256];
  int t = threadIdx.x;
  int v = (t < nbins) ? bin_cnt[t] : 0;
  s[t] = v;
  __syncthreads();
  for (int o = 1; o < 256; o <<= 1) {
    int u = (t >= o) ? s[t - o] : 0;
    __syncthreads();
    s[t] += u;
    __syncthreads();
  }
  int excl = s[t] - v;
  if (t < nbins) { bin_base[t] = excl; bin_cur[t] = excl; }
  if (t == 0) bin_base[nbins] = E;
}

// partition edges into dst bins; staged item = (src | dst<<16, weight_bits)
__global__ __launch_bounds__(256) void bin_part_kernel(
    const int* __restrict__ ei, const float* __restrict__ ew,
    int* __restrict__ bin_cur, uint2* __restrict__ ebin, int E)
{
  __shared__ uint2 spk[CHUNK];                       // 32 KB
  __shared__ int bcnt[256], boff[256], bcur[256], gbase[256], stmp[256];
  int t = threadIdx.x;
  int e0 = blockIdx.x * CHUNK;
  int m = min(CHUNK, E - e0);
  bcnt[t] = 0;
  __syncthreads();
  for (int i = t; i < m; i += 256)
    atomicAdd(&bcnt[ei[E + e0 + i] >> BSH], 1);
  __syncthreads();
  int v = bcnt[t];
  stmp[t] = v;
  __syncthreads();
  for (int o = 1; o < 256; o <<= 1) {
    int u = (t >= o) ? stmp[t - o] : 0;
    __syncthreads();
    stmp[t] += u;
    __syncthreads();
  }
  boff[t] = stmp[t] - v;
  bcur[t] = stmp[t] - v;
  if (v > 0) gbase[t] = atomicAdd(&bin_cur[t], v);
  __syncthreads();
  for (int i = t; i < m; i += 256) {
    unsigned d = (unsigned)ei[E + e0 + i];
    int b = d >> BSH;
    int p = atomicAdd(&bcur[b], 1);
    spk[p] = make_uint2((unsigned)ei[e0 + i] | (d << 16),
                        __float_as_uint(ew[e0 + i]));
  }
  __syncthreads();
  // staged items grouped by bin -> per-bin contiguous global writes
  for (int i = t; i < m; i += 256) {
    uint2 w = spk[i];
    int b = w.x >> 24;               // dst >> 8
    ebin[gbase[b] + (i - boff[b])] = w;
  }
}

// one block per bin: local hist + scan -> off[], scatter into bin's own
// ~32 KB window of packed[] (L2-resident, no write amplification)
__global__ __launch_bounds__(256) void fine_csr_kernel(
    const uint2* __restrict__ ebin, const int* __restrict__ bin_base,
    int* __restrict__ off, int2* __restrict__ packed, int N, int E)
{
  __shared__ int cnt[256], loff[256], cur[256], stmp[256];
  int t = threadIdx.x;
  int b = blockIdx.x;
  int ebeg = bin_base[b], eend = bin_base[b + 1];
  int m = eend - ebeg;
  cnt[t] = 0;
  __syncthreads();
  for (int i = t; i < m; i += 256)
    atomicAdd(&cnt[(ebin[ebeg + i].x >> 16) & 255], 1);
  __syncthreads();
  int v = cnt[t];
  stmp[t] = v;
  __syncthreads();
  for (int o = 1; o < 256; o <<= 1) {
    int u = (t >= o) ? stmp[t - o] : 0;
    __syncthreads();
    stmp[t] += u;
    __syncthreads();
  }
  loff[t] = stmp[t] - v;
  cur[t] = loff[t];
  int node = b * BINW + t;
  if (node < N) off[node] = ebeg + loff[t];
  if (b == 0 && t == 0) off[N] = E;
  __syncthreads();
  for (int i = t; i < m; i += 256) {
    uint2 w = ebin[ebeg + i];
    int dl = (w.x >> 16) & 255;
    int p = atomicAdd(&cur[dl], 1);
    packed[ebeg + p] = make_int2((int)(w.x & 0xffff), (int)w.y);
  }
}

// ---------------- fp32 -> fp16 row cache ----------------
__global__ __launch_bounds__(256) void tohalf_kernel(
    const float* __restrict__ x, __half* __restrict__ hh, int total)
{
  int i = (blockIdx.x * 256 + threadIdx.x) * 8;
  if (i >= total) return;
  float4 a = *(const float4*)(x + i);
  float4 b = *(const float4*)(x + i + 4);
  __half2 o[4];
  o[0] = __floats2half2_rn(a.x, a.y);
  o[1] = __floats2half2_rn(a.z, a.w);
  o[2] = __floats2half2_rn(b.x, b.y);
  o[3] = __floats2half2_rn(b.z, b.w);
  *(float4*)(hh + i) = *(float4*)o;
}

// ---------------- fused gather + GIN MLP + pooling ----------------
// Block = 256 (4 waves) = 64 nodes. Phase 0: each wave gathers its 16
// rows (8 edge-subgroups x 8 lanes, fp16 rows, fp32 acc, shfl reduce)
// straight into the swizzled LDS tile. Then GEMM phases with scalar
// (SGPR) weight loads. XOR-rotated LDS -> 2-way alias everywhere (free).
__global__ __launch_bounds__(256) void node_kernel(
    const __half* __restrict__ hh, const float* __restrict__ h,
    const int2* __restrict__ packed, const int* __restrict__ off,
    float* __restrict__ z, __half* __restrict__ hhout,
    const float* __restrict__ W1, const float* __restrict__ b1,
    const float* __restrict__ gamma, const float* __restrict__ beta,
    const float* __restrict__ bnm, const float* __restrict__ bnv,
    const float* __restrict__ W2, const float* __restrict__ b2,
    const float* __restrict__ epsv, const float* __restrict__ pmask,
    const int* __restrict__ batch, float* __restrict__ hcat,
    int layer, int N, int write_half)
{
  __shared__ float tileZ[DD * DD];
  __shared__ float tileT[DD * DD];
  const int wave = threadIdx.x >> 6;
  const int lane = threadIdx.x & 63;
  const int sub = lane >> 3;          // 0..7 edge subgroup
  const int ch0 = (lane & 7) * 8;     // 8 channels per lane
  const int n0 = blockIdx.x * 64;
  const int c0 = __builtin_amdgcn_readfirstlane(wave * 16);  // SGPR
  const float* W1l = W1 + layer * DD * DD;
  const float* W2l = W2 + layer * DD * DD;
  const float e1 = 1.0f + epsv[layer];

  // ---- phase 0: gather this wave's 16 rows directly into tileZ ----
  for (int i = 0; i < 16; ++i) {
    int r = c0 + i;
    int n = n0 + r;                  // wave-uniform
    float acc[8] = {0, 0, 0, 0, 0, 0, 0, 0};
    if (n < N) {
      int beg = off[n], end = off[n + 1];
      int e = beg + sub;
      for (; e + 8 < end; e += 16) {
        int2 p0 = packed[e];
        int2 p1 = packed[e + 8];
        float4 r0 = *(const float4*)(hh + (size_t)p0.x * DD + ch0);
        float4 r1 = *(const float4*)(hh + (size_t)p1.x * DD + ch0);
        float w0 = __int_as_float(p0.y), w1 = __int_as_float(p1.y);
        const __half2* H0 = (const __half2*)&r0;
        const __half2* H1 = (const __half2*)&r1;
        #pragma unroll
        for (int j = 0; j < 4; ++j) {
          float2 f0 = __half22float2(H0[j]);
          float2 f1 = __half22float2(H1[j]);
          acc[2 * j]     = fmaf(w0, f0.x, acc[2 * j]);
          acc[2 * j + 1] = fmaf(w0, f0.y, acc[2 * j + 1]);
          acc[2 * j]     = fmaf(w1, f1.x, acc[2 * j]);
          acc[2 * j + 1] = fmaf(w1, f1.y, acc[2 * j + 1]);
        }
      }
      for (; e < end; e += 8) {
        int2 p = packed[e];
        float4 rr = *(const float4*)(hh + (size_t)p.x * DD + ch0);
        float w = __int_as_float(p.y);
        const __half2* H = (const __half2*)&rr;
        #pragma unroll
        for (int j = 0; j < 4; ++j) {
          float2 f = __half22float2(H[j]);
          acc[2 * j]     = fmaf(w, f.x, acc[2 * j]);
          acc[2 * j + 1] = fmaf(w, f.y, acc[2 * j + 1]);
        }
      }
    }
    #pragma unroll
    for (int j = 0; j < 8; ++j) {
      acc[j] += __shfl_xor(acc[j], 8);
      acc[j] += __shfl_xor(acc[j], 16);
      acc[j] += __shfl_xor(acc[j], 32);
    }
    if (sub == 0) {
      float s[8] = {0, 0, 0, 0, 0, 0, 0, 0};
      if (n < N) {
        float4 s0 = *(const float4*)(h + (size_t)n * DD + ch0);
        float4 s1 = *(const float4*)(h + (size_t)n * DD + ch0 + 4);
        s[0] = s0.x; s[1] = s0.y; s[2] = s0.z; s[3] = s0.w;
        s[4] = s1.x; s[5] = s1.y; s[6] = s1.z; s[7] = s1.w;
      }
      #pragma unroll
      for (int j = 0; j < 8; ++j)
        tileZ[r * DD + ((ch0 + j + r) & 63)] = fmaf(e1, s[j], acc[j]);
    }
  }
  __syncthreads();

  // ---- phase 2: GEMM1, lane = node, channels c0..c0+15 ----
  float t[16];
  #pragma unroll
  for (int cc = 0; cc < 16; ++cc) t[cc] = 0.0f;
  #pragma unroll 2
  for (int k = 0; k < DD; ++k) {
    float zk = tileZ[lane * DD + ((k + lane) & 63)];
    #pragma unroll
    for (int cc = 0; cc < 16; ++cc)
      t[cc] = fmaf(zk, W1l[k * DD + c0 + cc], t[cc]);   // scalar W
  }
  #pragma unroll
  for (int cc = 0; cc < 16; ++cc) {
    int c = c0 + cc;
    float A = gamma[layer * DD + c] * rsqrtf(bnv[layer * DD + c] + 1e-5f);
    float B = fmaf(b1[layer * DD + c] - bnm[layer * DD + c], A,
                   beta[layer * DD + c]);
    tileT[lane * DD + ((c + lane) & 63)] = fmaxf(fmaf(t[cc], A, B), 0.0f);
  }
  __syncthreads();

  // ---- phase 3: GEMM2 ----
  #pragma unroll
  for (int cc = 0; cc < 16; ++cc) t[cc] = 0.0f;
  #pragma unroll 2
  for (int k = 0; k < DD; ++k) {
    float zk = tileT[lane * DD + ((k + lane) & 63)];
    #pragma unroll
    for (int cc = 0; cc < 16; ++cc)
      t[cc] = fmaf(zk, W2l[k * DD + c0 + cc], t[cc]);   // scalar W
  }
  #pragma unroll
  for (int cc = 0; cc < 16; ++cc) {
    int c = c0 + cc;
    tileZ[lane * DD + ((c + lane) & 63)] =
        fmaxf(t[cc] + b2[layer * DD + c], 0.0f);
  }
  __syncthreads();

  // ---- phase 4: store h_new + run-length pooled atomicAdd ----
  float accp = 0.0f;
  int gcur = -1;
  for (int i = 0; i < 16; ++i) {
    int r = c0 + i;
    int n = n0 + r;
    if (n >= N) break;
    float v = tileZ[r * DD + ((lane + r) & 63)];
    z[(size_t)n * DD + lane] = v;
    if (write_half) hhout[(size_t)n * DD + lane] = __float2half(v);
    int g = batch[n];
    if (g != gcur) {
      if (gcur >= 0) atomicAdd(&hcat[gcur * HC + layer * 128 + lane], accp);
      gcur = g; accp = 0.0f;
    }
    accp = fmaf(v, pmask[n], accp);
  }
  if (gcur >= 0) atomicAdd(&hcat[gcur * HC + layer * 128 + lane], accp);
}

// ---------------- center-node gather ----------------
__global__ __launch_bounds__(256) void center_kernel(
    const float* __restrict__ h, const int* __restrict__ mapping,
    float* __restrict__ hcat, int layer, int G)
{
  int gid = blockIdx.x * 256 + threadIdx.x;
  int g = gid >> 4, q = (gid & 15) * 4;
  if (g >= G) return;
  float4 v = *(const float4*)(h + (size_t)mapping[g] * DD + q);
  *(float4*)(hcat + g * HC + layer * 128 + 64 + q) = v;
}

// ---------------- final linear ----------------
__global__ __launch_bounds__(256) void final_kernel(
    const float* __restrict__ hcat, const float* __restrict__ lw,
    const float* __restrict__ lb, float* __restrict__ out, int G)
{
  int gid = blockIdx.x * 256 + threadIdx.x;
  int g = gid >> 5, s = gid & 31;
  if (g >= G) return;
  float acc = lb[s];
  #pragma unroll 4
  for (int j = 0; j < HC; ++j)
    acc = fmaf(hcat[g * HC + j], lw[j * SS + s], acc);
  out[g * SS + s] = acc;
}

extern "C" void kernel_launch(void* const* d_in, const int* in_sizes, int n_in,
                              void* d_out, int out_size, void* d_ws, size_t ws_size,
                              hipStream_t stream)
{
  const float* x     = (const float*)d_in[0];
  const float* ew    = (const float*)d_in[1];
  const float* pmask = (const float*)d_in[2];
  const float* W1    = (const float*)d_in[3];
  const float* b1    = (const float*)d_in[4];
  const float* gma   = (const float*)d_in[5];
  const float* bta   = (const float*)d_in[6];
  const float* bnm   = (const float*)d_in[7];
  const float* bnv   = (const float*)d_in[8];
  const float* W2    = (const float*)d_in[9];
  const float* b2    = (const float*)d_in[10];
  const float* epsv  = (const float*)d_in[11];
  const float* lw    = (const float*)d_in[12];
  const float* lb    = (const float*)d_in[13];
  const int*   ei    = (const int*)d_in[14];
  const int*   batch = (const int*)d_in[15];
  const int*   mapping = (const int*)d_in[16];

  const int N = in_sizes[2];     // 50000 (< 65536 required for packing)
  const int E = in_sizes[1];
  const int G = in_sizes[16];
  const int nbins = (N + BINW - 1) / BINW;   // <= 256
  const int nchunks = (E + CHUNK - 1) / CHUNK;

  float*  bufA = (float*)d_ws;                        // N*DD
  float*  bufB = bufA + (size_t)N * DD;               // N*DD
  float*  hcat = bufB + (size_t)N * DD;               // G*HC
  int*    off  = (int*)(hcat + (size_t)G * HC);       // N+1
  int*    bin_cnt  = off + (N + 1);                   // 256
  int*    bin_base = bin_cnt + 256;                   // 257
  int*    bin_cur  = bin_base + 257;                  // 257 (+pad)
  int2*   packed = (int2*)(bin_cur + 258);            // E
  __half* hhalf  = (__half*)(packed + (size_t)E);     // N*DD
  // ebin aliases bufB: live only during CSR build (before layer-1 output)
  uint2* ebin = (uint2*)bufB;                         // E (6.4MB < 12.8MB)
  float* fout = (float*)d_out;

  // ---- binned CSR build ----
  hipMemsetAsync(bin_cnt, 0, 256 * sizeof(int), stream);
  bin_count_kernel<<<256, 256, 0, stream>>>(ei, bin_cnt, E);
  bin_scan_kernel<<<1, 256, 0, stream>>>(bin_cnt, bin_base, bin_cur, nbins, E);
  bin_part_kernel<<<nchunks, 256, 0, stream>>>(ei, ew, bin_cur, ebin, E);
  fine_csr_kernel<<<nbins, 256, 0, stream>>>(ebin, bin_base, off, packed, N, E);

  hipMemsetAsync(hcat, 0, (size_t)G * HC * sizeof(float), stream);
  tohalf_kernel<<<(N * DD / 8 + 255) / 256, 256, 0, stream>>>(x, hhalf, N * DD);

  // ---- 3 GIN layers (fused gather+MLP+pool) ----
  const float* hsrc = x;
  float* zbuf = bufA;
  for (int layer = 0; layer < 3; ++layer) {
    node_kernel<<<(N + 63) / 64, 256, 0, stream>>>(
        hhalf, hsrc, packed, off, zbuf, hhalf,
        W1, b1, gma, bta, bnm, bnv, W2, b2,
        epsv, pmask, batch, hcat, layer, N, (layer < 2) ? 1 : 0);
    center_kernel<<<(G * DD / 4 + 255) / 256, 256, 0, stream>>>(
        zbuf, mapping, hcat, layer, G);
    hsrc = zbuf;
    zbuf = (zbuf == bufA) ? bufB : bufA;
  }
  final_kernel<<<(G * SS + 255) / 256, 256, 0, stream>>>(hcat, lw, lb, fout, G);
}